// Round 3
// baseline (62.893 us; speedup 1.0000x reference)
//
#include <hip/hip_runtime.h>
#include <math.h>

namespace {
constexpr int N_TOK = 16384;
constexpr int DIM   = 1024;
constexpr int NCLAN = 32;
constexpr int FPC_  = 64;
constexpr int HID   = 128;            // 2*FPC
constexpr int FTOT  = NCLAN * FPC_;   // 2048
constexpr float EPS = 1e-5f;
typedef float f4 __attribute__((ext_vector_type(4)));
}

// ---------------- pass 0: pure streaming zero-fill of d_out + ws init ----------------
// Persistent grid-stride, nt float4 stores: the m13 geometry that hits ~6.3 TB/s.
__global__ __launch_bounds__(256) void fill_zero_kernel(f4* __restrict__ out, int n_f4,
                                                        int* __restrict__ wsi) {
    if (blockIdx.x == 0 && threadIdx.x == 0) { wsi[0] = 0x7fffffff; wsi[1] = 0; }
    const f4 z = {0.f, 0.f, 0.f, 0.f};
    const int stride = gridDim.x * blockDim.x;
    for (int i = blockIdx.x * blockDim.x + threadIdx.x; i < n_f4; i += stride)
        __builtin_nontemporal_store(z, out + i);
}

// ---------------- pass 1: per-token argmax, global min -> sel ----------------
__global__ void clan_min_kernel(const float* __restrict__ xc, int* __restrict__ sel) {
    int i = blockIdx.x * blockDim.x + threadIdx.x;
    int bi = 0x7f7f7f7f;
    if (i < N_TOK) {
        const f4* row4 = (const f4*)(xc + (size_t)i * NCLAN);
        float best = -INFINITY; bi = 0;
        #pragma unroll
        for (int q = 0; q < NCLAN / 4; ++q) {
            f4 v = row4[q];
            #pragma unroll
            for (int j = 0; j < 4; ++j) {
                float f = v[j];
                if (f > best) { best = f; bi = q * 4 + j; }
            }
        }
    }
    #pragma unroll
    for (int off = 32; off > 0; off >>= 1) bi = min(bi, __shfl_down(bi, off));
    if ((threadIdx.x & 63) == 0) atomicMin(sel, bi);
}

// ---------------- pass 2: compact selected token indices ----------------
__global__ void compact_kernel(const float* __restrict__ xc, const int* __restrict__ sel_p,
                               int* __restrict__ cnt, int* __restrict__ list) {
    int i = blockIdx.x * blockDim.x + threadIdx.x;
    if (i >= N_TOK) return;
    const int sel = *sel_p;
    const f4* row4 = (const f4*)(xc + (size_t)i * NCLAN);
    float best = -INFINITY; int bi = 0;
    #pragma unroll
    for (int q = 0; q < NCLAN / 4; ++q) {
        f4 v = row4[q];
        #pragma unroll
        for (int j = 0; j < 4; ++j) {
            float f = v[j];
            if (f > best) { best = f; bi = q * 4 + j; }
        }
    }
    if (bi == sel) { int p = atomicAdd(cnt, 1); list[p] = i; }
}

// ---------------- pass 3: expert MLP on selected tokens (writes 256B/token) ----------------
__device__ __forceinline__ void expert_token(
    int tok, int sel,
    const float* __restrict__ x, const float* __restrict__ W1, const float* __restrict__ b1,
    const float* __restrict__ gamma, const float* __restrict__ beta,
    const float* __restrict__ W2, const float* __restrict__ b2,
    float* __restrict__ out, float* __restrict__ xs, float* __restrict__ rbuf,
    float* __restrict__ red)
{
    const int t = threadIdx.x;                       // 0..127, t == hidden channel
    // stage x row (1024 f32 = 4KB) into LDS, float4-vectorized, coalesced
    const f4* __restrict__ xr = (const f4*)(x + (size_t)tok * DIM);
    ((f4*)xs)[t]       = xr[t];
    ((f4*)xs)[t + HID] = xr[t + HID];
    __syncthreads();

    // h[t] = sum_d x[d] * W1[sel][d][t] + b1[sel][t]; W1 reads coalesced (stride H per d)
    const float* __restrict__ w1 = W1 + (size_t)sel * DIM * HID + t;
    float acc = b1[sel * HID + t];
    #pragma unroll 8
    for (int d = 0; d < DIM; ++d) acc = fmaf(xs[d], w1[(size_t)d * HID], acc);

    // LayerNorm over 128 channels: shfl reduce within each wave, combine 2 waves via LDS
    float s = acc, sq = acc * acc;
    #pragma unroll
    for (int off = 32; off > 0; off >>= 1) { s += __shfl_down(s, off); sq += __shfl_down(sq, off); }
    const int wv = t >> 6;
    if ((t & 63) == 0) { red[wv * 2] = s; red[wv * 2 + 1] = sq; }
    __syncthreads();
    const float mu  = (red[0] + red[2]) * (1.0f / HID);
    const float msq = (red[1] + red[3]) * (1.0f / HID);
    const float inv = rsqrtf(msq - mu * mu + EPS);
    float r = (acc - mu) * inv * gamma[sel * HID + t] + beta[sel * HID + t];
    rbuf[t] = fmaxf(r, 0.0f);
    __syncthreads();

    // out[f] = sum_h relu_h * W2[sel][h][f] + b2[sel][f]; threads 0..63 write 256B (2 full lines)
    if (t < FPC_) {
        const float* __restrict__ w2 = W2 + (size_t)sel * HID * FPC_ + t;
        float o = b2[sel * FPC_ + t];
        #pragma unroll 8
        for (int h = 0; h < HID; ++h) o = fmaf(rbuf[h], w2[(size_t)h * FPC_], o);
        out[(size_t)tok * FTOT + sel * FPC_ + t] = o;
    }
    __syncthreads();   // protect xs/rbuf/red for next grid-stride iteration
}

__global__ __launch_bounds__(128) void expert_list_kernel(
    const float* __restrict__ x, const float* __restrict__ W1, const float* __restrict__ b1,
    const float* __restrict__ gamma, const float* __restrict__ beta,
    const float* __restrict__ W2, const float* __restrict__ b2,
    const int* __restrict__ sel_p, const int* __restrict__ cnt_p, const int* __restrict__ list,
    float* __restrict__ out)
{
    __shared__ float xs[DIM];
    __shared__ float rbuf[HID];
    __shared__ float red[4];
    const int sel = *sel_p;
    const int M   = *cnt_p;
    for (int i = blockIdx.x; i < M; i += gridDim.x) {
        expert_token(list[i], sel, x, W1, b1, gamma, beta, W2, b2, out, xs, rbuf, red);
    }
}

extern "C" void kernel_launch(void* const* d_in, const int* in_sizes, int n_in,
                              void* d_out, int out_size, void* d_ws, size_t ws_size,
                              hipStream_t stream) {
    const float* x     = (const float*)d_in[0];
    const float* xc    = (const float*)d_in[1];
    const float* W1    = (const float*)d_in[2];
    const float* b1    = (const float*)d_in[3];
    const float* gamma = (const float*)d_in[4];
    const float* beta  = (const float*)d_in[5];
    const float* W2    = (const float*)d_in[6];
    const float* b2    = (const float*)d_in[7];
    float* out = (float*)d_out;

    int* wsi   = (int*)d_ws;
    int* sel_p = wsi;        // init'd by fill_zero_kernel
    int* cnt_p = wsi + 1;    // init'd by fill_zero_kernel
    int* list  = wsi + 2;

    const int n_f4 = out_size / 4;   // 8,388,608 float4s = 128 MiB
    fill_zero_kernel<<<2048, 256, 0, stream>>>((f4*)out, n_f4, wsi);
    clan_min_kernel<<<N_TOK / 256, 256, 0, stream>>>(xc, sel_p);
    compact_kernel<<<N_TOK / 256, 256, 0, stream>>>(xc, sel_p, cnt_p, list);
    expert_list_kernel<<<2048, 128, 0, stream>>>(x, W1, b1, gamma, beta, W2, b2,
                                                 sel_p, cnt_p, list, out);
}

// Round 4
// 45.805 us; speedup vs baseline: 1.3731x; 1.3731x over previous
//
#include <hip/hip_runtime.h>
#include <math.h>

namespace {
constexpr int N_TOK = 16384;
constexpr int DIM   = 1024;
constexpr int NCLAN = 32;
constexpr int FPC_  = 64;
constexpr int HID   = 128;            // 2*FPC
constexpr int FTOT  = NCLAN * FPC_;   // 2048
constexpr float EPS = 1e-5f;
typedef float f4 __attribute__((ext_vector_type(4)));
}

// ---------------- pass 1: per-token argmax -> am[], global min -> sel ----------------
__global__ void routing_kernel(const float* __restrict__ xc, int* __restrict__ sel,
                               int* __restrict__ am) {
    const int i = blockIdx.x * blockDim.x + threadIdx.x;   // one thread per token
    const f4* row4 = (const f4*)(xc + (size_t)i * NCLAN);
    float best = -INFINITY; int bi = 0;
    #pragma unroll
    for (int q = 0; q < NCLAN / 4; ++q) {
        f4 v = row4[q];
        #pragma unroll
        for (int j = 0; j < 4; ++j) {
            float f = v[j];
            if (f > best) { best = f; bi = q * 4 + j; }
        }
    }
    am[i] = bi;
    int mn = bi;
    #pragma unroll
    for (int off = 32; off > 0; off >>= 1) mn = min(mn, __shfl_down(mn, off));
    if ((threadIdx.x & 63) == 0) atomicMin(sel, mn);
}

// ---------------- pass 2: fused zero-fill + expert MLP ----------------
// One block (256 threads) per token row. Every block writes its full 8KB row;
// selected blocks (~1/32) additionally compute the MLP with a wide-ILP GEMV.
__global__ __launch_bounds__(256) void fused_kernel(
    const float* __restrict__ x,
    const float* __restrict__ W1, const float* __restrict__ b1,
    const float* __restrict__ gamma, const float* __restrict__ beta,
    const float* __restrict__ W2, const float* __restrict__ b2,
    const int* __restrict__ sel_p, const int* __restrict__ am,
    float* __restrict__ out)
{
    __shared__ float xs[DIM];       // 4KB staged x row
    __shared__ f4    part4[256];    // 4KB GEMV partials (reused by GEMV2)
    __shared__ f4    hbuf4[HID/4];  // 512B pre-LN hidden
    __shared__ f4    rbuf4[HID/4];  // 512B post-LN/ReLU
    __shared__ f4    obuf4[FPC_/4]; // 256B expert outputs
    __shared__ float red[2];        // LN reduce

    const int tok = blockIdx.x;
    const int t   = threadIdx.x;
    const int sel = *sel_p;                       // scalar, L2-hot
    const bool selected = (am[tok] == sel);       // block-uniform, one int load

    if (selected) {
        // stage x row: 256 threads x float4 = 4KB
        ((f4*)xs)[t] = ((const f4*)(x + (size_t)tok * DIM))[t];
        __syncthreads();

        // GEMV1: 32 ch-quads x 8 d-chunks. thread t: quad q=t&31, chunk c=t>>5.
        // 128 float4 loads/thread, 8-deep pipelined.
        {
            const int q = t & 31, c = t >> 5;
            const float* __restrict__ w1base = W1 + (size_t)sel * DIM * HID;
            f4 acc = {0.f, 0.f, 0.f, 0.f};
            const int d0 = c * (DIM / 8);
            #pragma unroll 8
            for (int d = d0; d < d0 + DIM / 8; ++d) {
                f4 w = ((const f4*)(w1base + (size_t)d * HID))[q];
                const float xv = xs[d];
                acc.x = fmaf(xv, w.x, acc.x);
                acc.y = fmaf(xv, w.y, acc.y);
                acc.z = fmaf(xv, w.z, acc.z);
                acc.w = fmaf(xv, w.w, acc.w);
            }
            part4[t] = acc;
        }
        __syncthreads();

        // reduce 8 chunks -> h quad; LN statistics via wave-0 shfl
        if (t < 32) {
            f4 h = part4[t];
            #pragma unroll
            for (int k = 1; k < 8; ++k) {
                f4 p = part4[t + 32 * k];
                h.x += p.x; h.y += p.y; h.z += p.z; h.w += p.w;
            }
            f4 bb = ((const f4*)(b1 + sel * HID))[t];
            h.x += bb.x; h.y += bb.y; h.z += bb.z; h.w += bb.w;
            hbuf4[t] = h;
            float s  = h.x + h.y + h.z + h.w;
            float sq = h.x * h.x + h.y * h.y + h.z * h.z + h.w * h.w;
            #pragma unroll
            for (int off = 16; off > 0; off >>= 1) {
                s  += __shfl_down(s, off);
                sq += __shfl_down(sq, off);
            }
            if (t == 0) { red[0] = s; red[1] = sq; }
        }
        __syncthreads();

        // LayerNorm + ReLU (threads 0..31, one quad each)
        if (t < 32) {
            const float mu  = red[0] * (1.0f / HID);
            const float msq = red[1] * (1.0f / HID);
            const float inv = rsqrtf(msq - mu * mu + EPS);
            f4 h = hbuf4[t];
            f4 g = ((const f4*)(gamma + sel * HID))[t];
            f4 b = ((const f4*)(beta  + sel * HID))[t];
            f4 r;
            r.x = fmaxf((h.x - mu) * inv * g.x + b.x, 0.f);
            r.y = fmaxf((h.y - mu) * inv * g.y + b.y, 0.f);
            r.z = fmaxf((h.z - mu) * inv * g.z + b.z, 0.f);
            r.w = fmaxf((h.w - mu) * inv * g.w + b.w, 0.f);
            rbuf4[t] = r;
        }
        __syncthreads();

        // GEMV2: 16 f-quads x 16 h-chunks of 8. thread t: fq=t&15, hc=t>>4.
        {
            const int fq = t & 15, hc = t >> 4;
            const float* __restrict__ w2base = W2 + (size_t)sel * HID * FPC_;
            const float* __restrict__ rb = (const float*)rbuf4;
            f4 acc = {0.f, 0.f, 0.f, 0.f};
            #pragma unroll 8
            for (int h = hc * 8; h < hc * 8 + 8; ++h) {
                f4 w = ((const f4*)(w2base + (size_t)h * FPC_))[fq];
                const float rv = rb[h];
                acc.x = fmaf(rv, w.x, acc.x);
                acc.y = fmaf(rv, w.y, acc.y);
                acc.z = fmaf(rv, w.z, acc.z);
                acc.w = fmaf(rv, w.w, acc.w);
            }
            part4[t] = acc;
        }
        __syncthreads();

        if (t < 16) {
            f4 o = part4[t];
            #pragma unroll
            for (int k = 1; k < 16; ++k) {
                f4 p = part4[t + 16 * k];
                o.x += p.x; o.y += p.y; o.z += p.z; o.w += p.w;
            }
            f4 bb = ((const f4*)(b2 + sel * FPC_))[t];
            o.x += bb.x; o.y += bb.y; o.z += bb.z; o.w += bb.w;
            obuf4[t] = o;
        }
        __syncthreads();
    }

    // --- write full 8KB row: zeros everywhere, expert quad-block substituted
    f4* __restrict__ orow = (f4*)(out + (size_t)tok * FTOT);
    const f4 z = {0.f, 0.f, 0.f, 0.f};
    if (!selected) {
        orow[t]       = z;
        orow[t + 256] = z;
    } else {
        const int blk_lo = sel * (FPC_ / 4);      // first f4 index of expert block
        #pragma unroll
        for (int k = 0; k < 2; ++k) {
            const int p = t + k * 256;
            f4 v = z;
            if (p >= blk_lo && p < blk_lo + (FPC_ / 4)) v = obuf4[p - blk_lo];
            orow[p] = v;
        }
    }
}

extern "C" void kernel_launch(void* const* d_in, const int* in_sizes, int n_in,
                              void* d_out, int out_size, void* d_ws, size_t ws_size,
                              hipStream_t stream) {
    const float* x     = (const float*)d_in[0];
    const float* xc    = (const float*)d_in[1];
    const float* W1    = (const float*)d_in[2];
    const float* b1    = (const float*)d_in[3];
    const float* gamma = (const float*)d_in[4];
    const float* beta  = (const float*)d_in[5];
    const float* W2    = (const float*)d_in[6];
    const float* b2    = (const float*)d_in[7];
    float* out = (float*)d_out;

    int* wsi   = (int*)d_ws;
    int* sel_p = wsi;          // scalar clan index
    int* am    = wsi + 2;      // per-token argmax, 64KB

    hipMemsetAsync(sel_p, 0x7f, sizeof(int), stream);   // sel = huge
    routing_kernel<<<N_TOK / 256, 256, 0, stream>>>(xc, sel_p, am);
    fused_kernel<<<N_TOK, 256, 0, stream>>>(x, W1, b1, gamma, beta, W2, b2,
                                            sel_p, am, out);
}